// Round 3
// baseline (140.606 us; speedup 1.0000x reference)
//
#include <hip/hip_runtime.h>

#define BSZ 8
#define NQ 2048
#define MP 64
#define DD 1024
#define K2ALL 2048       // packed interleaved ushort per (b,m) row: [m2, -2*m2*p]
#define BN 16            // query rows per block
#define LDKQ 2056        // K2ALL + 8 ushort pad
#define NSTEP 64         // DD/16 MFMA k-steps
#define NTILES (NQ / BN) // 128

typedef __bf16 bf16x8 __attribute__((ext_vector_type(8)));
typedef float f32x4 __attribute__((ext_vector_type(4)));
typedef unsigned short us8 __attribute__((ext_vector_type(8)));

__device__ __forceinline__ unsigned short f2bf(float f) {
    union { float f; unsigned int u; } v; v.f = f;
    unsigned int u = v.u;
    return (unsigned short)((u + 0x7FFFu + ((u >> 16) & 1u)) >> 16);  // RNE
}

// Pass 1: pack proto/mask -> bf16 [m2, -2*m2*p] interleaved + fp32 pterm.
__global__ __launch_bounds__(256) void pack_kernel(
    const float* __restrict__ proto,
    const float* __restrict__ mask,
    unsigned short* __restrict__ Pp,
    float* __restrict__ Pterm)
{
    const int row = blockIdx.x;          // b*64 + m
    const int t = threadIdx.x;

    const float4 mk = *(const float4*)(mask  + (size_t)row * DD + 4 * t);
    const float4 pr = *(const float4*)(proto + (size_t)row * DD + 4 * t);

    const float m2x = mk.x * mk.x, m2y = mk.y * mk.y,
                m2z = mk.z * mk.z, m2w = mk.w * mk.w;
    const float ax = mk.x * pr.x, ay = mk.y * pr.y,
                az = mk.z * pr.z, aw = mk.w * pr.w;
    float pacc = ax * ax + ay * ay + az * az + aw * aw;

    us8 o;
    o[0] = f2bf(m2x); o[1] = f2bf(-2.f * m2x * pr.x);
    o[2] = f2bf(m2y); o[3] = f2bf(-2.f * m2y * pr.y);
    o[4] = f2bf(m2z); o[5] = f2bf(-2.f * m2z * pr.z);
    o[6] = f2bf(m2w); o[7] = f2bf(-2.f * m2w * pr.w);
    *(us8*)(Pp + (size_t)row * K2ALL + 8 * t) = o;

    __shared__ float red[4];
    #pragma unroll
    for (int off = 32; off > 0; off >>= 1)
        pacc += __shfl_down(pacc, off, 64);
    const int lane = t & 63, w = t >> 6;
    if (lane == 0) red[w] = pacc;
    __syncthreads();
    if (t == 0) Pterm[row] = red[0] + red[1] + red[2] + red[3];
}

// Pass 2: 1024 blocks (b = bid&7), 256 threads, ONE barrier.
// Phase A: stage full 16x1024 query tile as interleaved bf16 [q^2,q] in LDS
//          (16 float4 loads/thread in flight -> deep MLP for HBM).
// Phase B: 64 MFMA k-steps; B streamed global(L2)->reg, depth-8 queue.
__global__ __launch_bounds__(256) void proto_main_kernel(
    const float* __restrict__ query,
    const unsigned short* __restrict__ Pp,
    const float* __restrict__ Pterm,
    const float* __restrict__ scale,
    float* __restrict__ out)
{
    __shared__ unsigned short Qs[BN][LDKQ];   // 65.8 KB -> 2 blocks/CU

    const int tid = threadIdx.x;
    const int bid = blockIdx.x;
    const int b  = bid & 7;
    const int n0 = (bid >> 3) * BN;

    const int qrow = tid >> 4;           // 0..15
    const int qc   = tid & 15;
    const float* qptr = query + ((size_t)b * NQ + n0 + qrow) * DD + 4 * qc;

    const int lane = tid & 63;
    const int wid  = tid >> 6;           // m-slice
    const int lrow = lane & 15;
    const int lq   = (lane >> 4) * 8;

    const int mcol = 16 * wid + lrow;
    const unsigned short* bptr = Pp + ((size_t)(b * MP + mcol)) * K2ALL + lq;

    // ---- Phase A: stage query tile (one barrier total) ----
    float4 qv[16];
    #pragma unroll
    for (int p = 0; p < 16; ++p)
        qv[p] = *(const float4*)(qptr + 64 * p);

    const float pt = Pterm[b * MP + mcol];       // L2 scalar, hidden here
    const float sc = scale[0] * (1.0f / (float)DD);

    #pragma unroll
    for (int p = 0; p < 16; ++p) {
        const float4 q = qv[p];
        us8 o;
        o[0] = f2bf(q.x * q.x); o[1] = f2bf(q.x);
        o[2] = f2bf(q.y * q.y); o[3] = f2bf(q.y);
        o[4] = f2bf(q.z * q.z); o[5] = f2bf(q.z);
        o[6] = f2bf(q.w * q.w); o[7] = f2bf(q.w);
        *(us8*)(&Qs[qrow][8 * qc + 128 * p]) = o;
    }
    __syncthreads();

    // ---- Phase B: barrier-free MFMA stream, depth-8 B queue ----
    f32x4 acc = (f32x4){0.f, 0.f, 0.f, 0.f};
    bf16x8 bq[8];
    #pragma unroll
    for (int i = 0; i < 8; ++i)
        bq[i] = *(const bf16x8*)(bptr + 32 * i);

    #pragma unroll
    for (int g = 0; g < NSTEP; g += 8) {
        #pragma unroll
        for (int j = 0; j < 8; ++j) {
            const bf16x8 bb = bq[j];
            if (g + 8 + j < NSTEP)
                bq[j] = *(const bf16x8*)(bptr + 32 * (g + 8 + j));
            const bf16x8 a = *(const bf16x8*)(&Qs[lrow][32 * (g + j) + lq]);
            acc = __builtin_amdgcn_mfma_f32_16x16x32_bf16(a, bb, acc, 0, 0, 0);
        }
    }

    // ---- epilogue: n = n0 + (lane>>4)*4 + r, m = mcol ----
    const size_t ob = ((size_t)b * NQ + (size_t)(n0 + (lane >> 4) * 4)) * MP + mcol;
    #pragma unroll
    for (int r = 0; r < 4; ++r)
        out[ob + (size_t)r * MP] = (acc[r] + pt) * sc;
}

extern "C" void kernel_launch(void* const* d_in, const int* in_sizes, int n_in,
                              void* d_out, int out_size, void* d_ws, size_t ws_size,
                              hipStream_t stream) {
    (void)in_sizes; (void)n_in; (void)ws_size; (void)out_size;
    const float* proto = (const float*)d_in[0];
    const float* mask  = (const float*)d_in[1];
    const float* query = (const float*)d_in[2];
    const float* scale = (const float*)d_in[5];
    float* out = (float*)d_out;

    unsigned short* Pp = (unsigned short*)d_ws;                           // 2 MiB
    float* Pterm = (float*)((char*)d_ws + (size_t)BSZ * MP * K2ALL * 2);  // +2 KiB

    pack_kernel<<<dim3(BSZ * MP), dim3(256), 0, stream>>>(proto, mask, Pp, Pterm);
    proto_main_kernel<<<dim3(BSZ * NTILES), dim3(256), 0, stream>>>(
        query, Pp, Pterm, scale, out);
}

// Round 4
// 121.849 us; speedup vs baseline: 1.1539x; 1.1539x over previous
//
#include <hip/hip_runtime.h>

#define BSZ 8
#define NQ 2048
#define MP 64
#define DD 1024
#define K2ALL 2048       // interleaved ushort per (b,m) row: [m2, -2*m2*p]
#define BN 16            // query rows per block
#define LDKQ 2056        // K2ALL + 8 ushort pad
#define NSTEP 64         // k-steps (2048 interleaved / 32 per MFMA)
#define NTILES (NQ / BN) // 128

typedef __bf16 bf16x8 __attribute__((ext_vector_type(8)));
typedef float f32x4 __attribute__((ext_vector_type(4)));
typedef unsigned short us8 __attribute__((ext_vector_type(8)));

__device__ __forceinline__ unsigned short f2bf(float f) {
    union { float f; unsigned int u; } v; v.f = f;
    unsigned int u = v.u;
    return (unsigned short)((u + 0x7FFFu + ((u >> 16) & 1u)) >> 16);  // RNE
}

// Pass 1: pack proto/mask -> bf16 [m2, -2*m2*p] in MFMA *fragment order* +
// fp32 pterm. Fragment layout: flat ushort index
//   ((((b*4 + mt)*64 + s)*64) + lane)*8 + e
// where mt=m>>4, s=k32-step, lane=(t&3)*16 + (m&15), e=0..7.
// A wave's per-step B-load in the main kernel is then one contiguous 1 KB.
__global__ __launch_bounds__(256) void pack_kernel(
    const float* __restrict__ proto,
    const float* __restrict__ mask,
    unsigned short* __restrict__ Pf,
    float* __restrict__ Pterm)
{
    const int row = blockIdx.x;          // b*64 + m
    const int m = row & 63;
    const int b = row >> 6;
    const int t = threadIdx.x;           // d-group: d = 4t..4t+3 -> k = 8t..8t+7

    const float4 mk = *(const float4*)(mask  + (size_t)row * DD + 4 * t);
    const float4 pr = *(const float4*)(proto + (size_t)row * DD + 4 * t);

    const float m2x = mk.x * mk.x, m2y = mk.y * mk.y,
                m2z = mk.z * mk.z, m2w = mk.w * mk.w;
    const float ax = mk.x * pr.x, ay = mk.y * pr.y,
                az = mk.z * pr.z, aw = mk.w * pr.w;
    float pacc = ax * ax + ay * ay + az * az + aw * aw;

    us8 o;
    o[0] = f2bf(m2x); o[1] = f2bf(-2.f * m2x * pr.x);
    o[2] = f2bf(m2y); o[3] = f2bf(-2.f * m2y * pr.y);
    o[4] = f2bf(m2z); o[5] = f2bf(-2.f * m2z * pr.z);
    o[6] = f2bf(m2w); o[7] = f2bf(-2.f * m2w * pr.w);

    const int mt   = m >> 4;
    const int s    = t >> 2;                      // k32 step 0..63
    const int lane = (t & 3) * 16 + (m & 15);     // consuming lane
    const size_t idx = ((((size_t)(b * 4 + mt)) * 64 + s) * 64 + lane) * 8;
    *(us8*)(Pf + idx) = o;

    __shared__ float red[4];
    #pragma unroll
    for (int off = 32; off > 0; off >>= 1)
        pacc += __shfl_down(pacc, off, 64);
    const int lane64 = t & 63, w = t >> 6;
    if (lane64 == 0) red[w] = pacc;
    __syncthreads();
    if (t == 0) Pterm[row] = red[0] + red[1] + red[2] + red[3];
}

// Pass 2: 1024 blocks (b = bid&7 -> XCD-affine), 256 threads, ONE barrier.
// Phase A: stage full 16x1024 query tile as interleaved bf16 [q^2,q] in LDS.
// Phase B: 64 MFMA k-steps; B streamed from fragment-packed buffer —
//          one contiguous 1 KB global(L2) load per wave per step, depth-8 queue.
__global__ __launch_bounds__(256) void proto_main_kernel(
    const float* __restrict__ query,
    const unsigned short* __restrict__ Pf,
    const float* __restrict__ Pterm,
    const float* __restrict__ scale,
    float* __restrict__ out)
{
    __shared__ unsigned short Qs[BN][LDKQ];   // 65.8 KB -> 2 blocks/CU

    const int tid = threadIdx.x;
    const int bid = blockIdx.x;
    const int b  = bid & 7;
    const int n0 = (bid >> 3) * BN;

    const int qrow = tid >> 4;           // 0..15
    const int qc   = tid & 15;
    const float* qptr = query + ((size_t)b * NQ + n0 + qrow) * DD + 4 * qc;

    const int lane = tid & 63;
    const int wid  = tid >> 6;           // m-tile owner
    const int lrow = lane & 15;
    const int lq   = (lane >> 4) * 8;

    const int mcol = 16 * wid + lrow;
    // fragment-packed B: wave base, step stride = 512 ushorts (1 KB)
    const unsigned short* bbase =
        Pf + (((size_t)(b * 4 + wid)) * 64) * 512 + (size_t)lane * 8;

    // ---- Phase A: stage query tile (one barrier total) ----
    float4 qv[16];
    #pragma unroll
    for (int p = 0; p < 16; ++p)
        qv[p] = *(const float4*)(qptr + 64 * p);

    const float pt = Pterm[b * MP + mcol];
    const float sc = scale[0] * (1.0f / (float)DD);

    #pragma unroll
    for (int p = 0; p < 16; ++p) {
        const float4 q = qv[p];
        us8 o;
        o[0] = f2bf(q.x * q.x); o[1] = f2bf(q.x);
        o[2] = f2bf(q.y * q.y); o[3] = f2bf(q.y);
        o[4] = f2bf(q.z * q.z); o[5] = f2bf(q.z);
        o[6] = f2bf(q.w * q.w); o[7] = f2bf(q.w);
        *(us8*)(&Qs[qrow][8 * qc + 128 * p]) = o;
    }
    __syncthreads();

    // ---- Phase B: barrier-free MFMA stream, depth-8 contiguous B queue ----
    f32x4 acc = (f32x4){0.f, 0.f, 0.f, 0.f};
    bf16x8 bq[8];
    #pragma unroll
    for (int i = 0; i < 8; ++i)
        bq[i] = *(const bf16x8*)(bbase + (size_t)i * 512);

    #pragma unroll
    for (int g = 0; g < NSTEP; g += 8) {
        #pragma unroll
        for (int j = 0; j < 8; ++j) {
            const bf16x8 bb = bq[j];
            if (g + 8 + j < NSTEP)
                bq[j] = *(const bf16x8*)(bbase + (size_t)(g + 8 + j) * 512);
            const bf16x8 a = *(const bf16x8*)(&Qs[lrow][32 * (g + j) + lq]);
            acc = __builtin_amdgcn_mfma_f32_16x16x32_bf16(a, bb, acc, 0, 0, 0);
        }
    }

    // ---- epilogue: n = n0 + (lane>>4)*4 + r, m = mcol ----
    const size_t ob = ((size_t)b * NQ + (size_t)(n0 + (lane >> 4) * 4)) * MP + mcol;
    #pragma unroll
    for (int r = 0; r < 4; ++r)
        out[ob + (size_t)r * MP] = (acc[r] + pt) * sc;
}

extern "C" void kernel_launch(void* const* d_in, const int* in_sizes, int n_in,
                              void* d_out, int out_size, void* d_ws, size_t ws_size,
                              hipStream_t stream) {
    (void)in_sizes; (void)n_in; (void)ws_size; (void)out_size;
    const float* proto = (const float*)d_in[0];
    const float* mask  = (const float*)d_in[1];
    const float* query = (const float*)d_in[2];
    const float* scale = (const float*)d_in[5];
    float* out = (float*)d_out;

    unsigned short* Pf = (unsigned short*)d_ws;                           // 2 MiB
    float* Pterm = (float*)((char*)d_ws + (size_t)BSZ * MP * K2ALL * 2);  // +2 KiB

    pack_kernel<<<dim3(BSZ * MP), dim3(256), 0, stream>>>(proto, mask, Pf, Pterm);
    proto_main_kernel<<<dim3(BSZ * NTILES), dim3(256), 0, stream>>>(
        query, Pf, Pterm, scale, out);
}